// Round 1
// baseline (2002.891 us; speedup 1.0000x reference)
//
#include <hip/hip_runtime.h>
#include <float.h>
#include <math.h>

#define N_ROWS 4096
#define M_TGT  65536
#define DDIM   256
#define BM     64
#define BN     64
#define KC     16
#define S_STRIPS 32
#define PADM   68   // BM + 4 pad: keeps float4 alignment, breaks bank conflicts

// ---------------------------------------------------------------------------
// Kernel 1: row norms for x (N rows) and target_set (M rows).
// One wave (64 lanes) per row; each lane loads float4 (4 elems) -> 256 total.
// ---------------------------------------------------------------------------
__global__ __launch_bounds__(256) void norms_kernel(
    const float* __restrict__ x, const float* __restrict__ t,
    float* __restrict__ xn, float* __restrict__ tn) {
  int wave = threadIdx.x >> 6;
  int lane = threadIdx.x & 63;
  int row  = blockIdx.x * 4 + wave;
  const float* src;
  float* dst;
  if (row < N_ROWS) {
    src = x + (size_t)row * DDIM;
    dst = xn + row;
  } else {
    int r = row - N_ROWS;
    if (r >= M_TGT) return;
    src = t + (size_t)r * DDIM;
    dst = tn + r;
  }
  float4 v = *(const float4*)(src + lane * 4);
  float s = v.x * v.x + v.y * v.y + v.z * v.z + v.w * v.w;
  #pragma unroll
  for (int off = 32; off > 0; off >>= 1) s += __shfl_xor(s, off, 64);
  if (lane == 0) *dst = s;
}

// ---------------------------------------------------------------------------
// Kernel 2: main tiled distance + running min.
// Block = 256 threads = 16x16 thread grid, 4x4 micro-tile each.
// blockIdx.x = row block (64 rows), blockIdx.y = target strip (2048 targets).
// LDS tiles stored k-major: s[k][row/col] so fragment reads are float4.
// ---------------------------------------------------------------------------
__global__ __launch_bounds__(256) void nn_main(
    const float* __restrict__ x, const float* __restrict__ t,
    const float* __restrict__ xn, const float* __restrict__ tn,
    float* __restrict__ pmin, int* __restrict__ pidx) {
  __shared__ float sx[KC][PADM];
  __shared__ float st[KC][PADM];

  const int tid   = threadIdx.x;
  const int rb    = blockIdx.x;        // 0..63
  const int strip = blockIdx.y;        // 0..S_STRIPS-1
  const int tx = tid & 15;
  const int ty = tid >> 4;
  const int row0 = rb * BM;
  const int col_start = strip * (M_TGT / S_STRIPS);
  const int ntiles = (M_TGT / S_STRIPS) / BN;   // 32

  // staging mapping: each thread loads one float4 along k for one row/col
  const int srow = tid >> 2;           // 0..63
  const int kq   = (tid & 3) * 4;      // 0,4,8,12

  float runMin[4];
  int   runIdx[4];
  #pragma unroll
  for (int r = 0; r < 4; ++r) { runMin[r] = FLT_MAX; runIdx[r] = 0; }

  // hoist x norms for this thread's 4 rows
  float xnr[4];
  #pragma unroll
  for (int r = 0; r < 4; ++r) xnr[r] = xn[row0 + ty * 4 + r];

  for (int tile = 0; tile < ntiles; ++tile) {
    const int cb = col_start + tile * BN;

    float acc[4][4];
    #pragma unroll
    for (int r = 0; r < 4; ++r)
      #pragma unroll
      for (int c = 0; c < 4; ++c) acc[r][c] = 0.0f;

    #pragma unroll 1
    for (int kc = 0; kc < DDIM; kc += KC) {
      // issue global loads early (overlap previous chunk's compute)
      float4 xv = *(const float4*)(x + (size_t)(row0 + srow) * DDIM + kc + kq);
      float4 tv = *(const float4*)(t + (size_t)(cb   + srow) * DDIM + kc + kq);
      __syncthreads();  // previous chunk's compute done before overwrite
      sx[kq + 0][srow] = xv.x; sx[kq + 1][srow] = xv.y;
      sx[kq + 2][srow] = xv.z; sx[kq + 3][srow] = xv.w;
      st[kq + 0][srow] = tv.x; st[kq + 1][srow] = tv.y;
      st[kq + 2][srow] = tv.z; st[kq + 3][srow] = tv.w;
      __syncthreads();

      #pragma unroll
      for (int k = 0; k < KC; ++k) {
        float4 xa = *(const float4*)&sx[k][ty * 4];
        float4 tb = *(const float4*)&st[k][tx * 4];
        float xr[4] = {xa.x, xa.y, xa.z, xa.w};
        float tc[4] = {tb.x, tb.y, tb.z, tb.w};
        #pragma unroll
        for (int r = 0; r < 4; ++r)
          #pragma unroll
          for (int c = 0; c < 4; ++c)
            acc[r][c] = fmaf(xr[r], tc[c], acc[r][c]);
      }
    }

    // epilogue: d2 = xn + tn - 2*dot; running min with first-index semantics
    #pragma unroll
    for (int r = 0; r < 4; ++r) {
      #pragma unroll
      for (int c = 0; c < 4; ++c) {
        int col = cb + tx * 4 + c;
        float d2 = xnr[r] + tn[col] - 2.0f * acc[r][c];
        if (d2 < runMin[r]) { runMin[r] = d2; runIdx[r] = col; }
      }
    }
  }

  // cross-thread reduce (over tx) via LDS reuse
  __syncthreads();
  float* redv = &sx[0][0];          // 64 rows x 16 tx = 1024 <= 16*68
  int*   redi = (int*)&st[0][0];
  #pragma unroll
  for (int r = 0; r < 4; ++r) {
    int lrow = ty * 4 + r;
    redv[lrow * 16 + tx] = runMin[r];
    redi[lrow * 16 + tx] = runIdx[r];
  }
  __syncthreads();
  if (tid < 64) {
    float best = FLT_MAX;
    int bi = 0;
    #pragma unroll
    for (int j = 0; j < 16; ++j) {
      float v = redv[tid * 16 + j];
      int   i = redi[tid * 16 + j];
      if (v < best || (v == best && i < bi)) { best = v; bi = i; }
    }
    int grow = row0 + tid;
    pmin[(size_t)grow * S_STRIPS + strip] = best;
    pidx[(size_t)grow * S_STRIPS + strip] = bi;
  }
}

// ---------------------------------------------------------------------------
// Kernel 3: reduce strips per row, sqrt, write values + indices(as float).
// ---------------------------------------------------------------------------
__global__ __launch_bounds__(256) void reduce_final(
    const float* __restrict__ pmin, const int* __restrict__ pidx,
    float* __restrict__ out) {
  int row = blockIdx.x * 256 + threadIdx.x;
  if (row >= N_ROWS) return;
  float best = FLT_MAX;
  int bi = 0;
  #pragma unroll 4
  for (int s = 0; s < S_STRIPS; ++s) {
    float v = pmin[(size_t)row * S_STRIPS + s];
    int   i = pidx[(size_t)row * S_STRIPS + s];
    if (v < best || (v == best && i < bi)) { best = v; bi = i; }
  }
  out[row] = sqrtf(fmaxf(best, 0.0f));
  out[N_ROWS + row] = (float)bi;
}

// ---------------------------------------------------------------------------
extern "C" void kernel_launch(void* const* d_in, const int* in_sizes, int n_in,
                              void* d_out, int out_size, void* d_ws, size_t ws_size,
                              hipStream_t stream) {
  const float* x = (const float*)d_in[0];
  const float* t = (const float*)d_in[1];

  float* ws   = (float*)d_ws;
  float* xn   = ws;                        // 4096
  float* tn   = ws + N_ROWS;               // 65536
  float* pmin = ws + N_ROWS + M_TGT;       // 4096*32
  int*   pidx = (int*)(ws + N_ROWS + M_TGT + N_ROWS * S_STRIPS);

  norms_kernel<<<(N_ROWS + M_TGT) / 4, 256, 0, stream>>>(x, t, xn, tn);

  dim3 grid(N_ROWS / BM, S_STRIPS);
  nn_main<<<grid, 256, 0, stream>>>(x, t, xn, tn, pmin, pidx);

  reduce_final<<<(N_ROWS + 255) / 256, 256, 0, stream>>>(pmin, pidx, (float*)d_out);
}

// Round 2
// 328.940 us; speedup vs baseline: 6.0889x; 6.0889x over previous
//
#include <hip/hip_runtime.h>
#include <float.h>
#include <math.h>

#define N_ROWS 4096
#define M_TGT  65536
#define DDIM   256

// ---------------------------------------------------------------------------
// Shared types/helpers
// ---------------------------------------------------------------------------
typedef short bf16x8 __attribute__((ext_vector_type(8)));
typedef float f32x4 __attribute__((ext_vector_type(4)));
typedef unsigned short ushort8_t __attribute__((ext_vector_type(8)));

__device__ inline unsigned short f2bf(float f) {
  union { float f; unsigned u; } c; c.f = f;
  unsigned u = c.u;
  unsigned r = (u + 0x7FFFu + ((u >> 16) & 1u)) >> 16;  // RNE
  return (unsigned short)r;
}

__device__ inline void gload_lds16(const void* g, void* l) {
  __builtin_amdgcn_global_load_lds(
      (const __attribute__((address_space(1))) void*)g,
      (__attribute__((address_space(3))) void*)l, 16, 0, 0);
}

// ---------------------------------------------------------------------------
// Kernel: row norms for x and t (exact fp32, same reduction order every call)
// ---------------------------------------------------------------------------
__global__ __launch_bounds__(256) void norms_kernel(
    const float* __restrict__ x, const float* __restrict__ t,
    float* __restrict__ xn, float* __restrict__ tn) {
  int wave = threadIdx.x >> 6;
  int lane = threadIdx.x & 63;
  int row  = blockIdx.x * 4 + wave;
  const float* src;
  float* dst;
  if (row < N_ROWS) {
    src = x + (size_t)row * DDIM;
    dst = xn + row;
  } else {
    int r = row - N_ROWS;
    if (r >= M_TGT) return;
    src = t + (size_t)r * DDIM;
    dst = tn + r;
  }
  float4 v = *(const float4*)(src + lane * 4);
  float s = v.x * v.x + v.y * v.y + v.z * v.z + v.w * v.w;
  #pragma unroll
  for (int off = 32; off > 0; off >>= 1) s += __shfl_xor(s, off, 64);
  if (lane == 0) *dst = s;
}

// ---------------------------------------------------------------------------
// Kernel: fp32 -> bf16 conversion, 8 elems/thread
// ---------------------------------------------------------------------------
__global__ __launch_bounds__(256) void convert_bf16_kernel(
    const float* __restrict__ src, unsigned short* __restrict__ dst, int n8) {
  int i = blockIdx.x * 256 + threadIdx.x;
  if (i >= n8) return;
  float4 a = *(const float4*)(src + (size_t)i * 8);
  float4 b = *(const float4*)(src + (size_t)i * 8 + 4);
  ushort8_t o;
  o[0] = f2bf(a.x); o[1] = f2bf(a.y); o[2] = f2bf(a.z); o[3] = f2bf(a.w);
  o[4] = f2bf(b.x); o[5] = f2bf(b.y); o[6] = f2bf(b.z); o[7] = f2bf(b.w);
  *(ushort8_t*)(dst + (size_t)i * 8) = o;
}

// ---------------------------------------------------------------------------
// Kernel: bf16 MFMA screening GEMM.
// Block = 256 threads (4 waves, 2x2 wave grid), tile 128x128, BK=32.
// Each wave: 4x4 fragments of mfma_f32_16x16x32_bf16 (64x64 per wave).
// Output: per (row, 128-col-tile) min of (tn[col] - 2*dot_bf16)  [8 MB].
// LDS layout: [row][32] bf16 row-major, 16B slots XOR-swizzled by row&3
// (applied on the global SOURCE address, since global_load_lds writes
//  linearly: rule 21 both-sides-or-neither).
// ---------------------------------------------------------------------------
#define GBM 128
#define GBN 128
#define GBK 32
#define NCB (M_TGT / GBN)          // 512 col tiles
#define MARGIN 1.5f

__global__ __launch_bounds__(256) void nn_gemm_bf16(
    const unsigned short* __restrict__ xb, const unsigned short* __restrict__ tb,
    const float* __restrict__ tn, float* __restrict__ bmv) {
  __shared__ unsigned short sA[GBM * GBK];   // 8 KB
  __shared__ unsigned short sB[GBN * GBK];   // 8 KB

  const int tid  = threadIdx.x;
  const int lane = tid & 63;
  const int wid  = tid >> 6;
  const int wr   = wid >> 1, wc = wid & 1;

  // XCD-aware bijective swizzle (16384 % 8 == 0)
  int bid = blockIdx.x;
  int wg  = (bid & 7) * 2048 + (bid >> 3);
  int rb  = wg >> 9;               // 0..31
  int cb  = wg & (NCB - 1);        // 0..511
  const int row0 = rb * GBM;
  const int col0 = cb * GBN;

  // staging map: idx = c*256 + tid; 16B chunk -> row = idx>>2, phys slot idx&3
  const int r0i = tid >> 2,         s0 = (tid & 3) ^ (r0i & 3);
  const int r1i = (256 + tid) >> 2, s1 = ((256 + tid) & 3) ^ (r1i & 3);
  char* sAc = (char*)sA;
  char* sBc = (char*)sB;
  char* ldsA0 = sAc + wid * 1024;
  char* ldsA1 = sAc + 4096 + wid * 1024;
  char* ldsB0 = sBc + wid * 1024;
  char* ldsB1 = sBc + 4096 + wid * 1024;

  f32x4 acc[4][4];
  const f32x4 zero = {0.0f, 0.0f, 0.0f, 0.0f};
  #pragma unroll
  for (int m = 0; m < 4; ++m)
    #pragma unroll
    for (int n = 0; n < 4; ++n) acc[m][n] = zero;

  for (int kc = 0; kc < DDIM; kc += GBK) {
    __syncthreads();   // previous step's LDS reads complete
    gload_lds16(xb + (size_t)(row0 + r0i) * DDIM + kc + s0 * 8, ldsA0);
    gload_lds16(xb + (size_t)(row0 + r1i) * DDIM + kc + s1 * 8, ldsA1);
    gload_lds16(tb + (size_t)(col0 + r0i) * DDIM + kc + s0 * 8, ldsB0);
    gload_lds16(tb + (size_t)(col0 + r1i) * DDIM + kc + s1 * 8, ldsB1);
    __syncthreads();   // compiler drains vmcnt(0) before barrier -> data ready

    const int cgrp = lane >> 4;    // logical 8-elem k-chunk
    bf16x8 af[4], bfr[4];
    #pragma unroll
    for (int m = 0; m < 4; ++m) {
      int row = wr * 64 + m * 16 + (lane & 15);
      int p = cgrp ^ (row & 3);
      af[m] = *(const bf16x8*)(sAc + row * 64 + p * 16);
    }
    #pragma unroll
    for (int n = 0; n < 4; ++n) {
      int row = wc * 64 + n * 16 + (lane & 15);
      int p = cgrp ^ (row & 3);
      bfr[n] = *(const bf16x8*)(sBc + row * 64 + p * 16);
    }
    #pragma unroll
    for (int m = 0; m < 4; ++m)
      #pragma unroll
      for (int n = 0; n < 4; ++n)
        acc[m][n] = __builtin_amdgcn_mfma_f32_16x16x32_bf16(af[m], bfr[n], acc[m][n], 0, 0, 0);
  }

  // ---- epilogue: per-row min of (tn[col] - 2*dot) over this 128-col tile ----
  float tnc[4];
  #pragma unroll
  for (int n = 0; n < 4; ++n)
    tnc[n] = tn[col0 + wc * 64 + n * 16 + (lane & 15)];

  __syncthreads();                  // done reading sA/sB as tiles
  float* emin = (float*)sA;         // [2 wc][128 rows]

  #pragma unroll
  for (int m = 0; m < 4; ++m) {
    float bv[4];
    #pragma unroll
    for (int j = 0; j < 4; ++j) bv[j] = FLT_MAX;
    #pragma unroll
    for (int n = 0; n < 4; ++n)
      #pragma unroll
      for (int j = 0; j < 4; ++j)
        bv[j] = fminf(bv[j], tnc[n] - 2.0f * acc[m][n][j]);
    // min across the 16 lanes of each (lane>>4) group
    #pragma unroll
    for (int off = 1; off < 16; off <<= 1)
      #pragma unroll
      for (int j = 0; j < 4; ++j)
        bv[j] = fminf(bv[j], __shfl_xor(bv[j], off, 64));
    if ((lane & 15) == 0) {
      int rbase = wr * 64 + m * 16 + (lane >> 4) * 4;
      #pragma unroll
      for (int j = 0; j < 4; ++j)
        emin[wc * 128 + rbase + j] = bv[j];
    }
  }
  __syncthreads();
  if (tid < 128) {
    float v = fminf(emin[tid], emin[128 + tid]);
    bmv[(size_t)(row0 + tid) * NCB + cb] = v;
  }
}

// ---------------------------------------------------------------------------
// Kernel: per-row candidate selection + exact fp32 verification.
// One block (256 thr) per row. Scan 512 tile-mins, take tiles within MARGIN
// of the min, recompute exact d2 for their 128 cols, reduce with first-index
// tie-break (matches jnp.argmin).
// ---------------------------------------------------------------------------
__global__ __launch_bounds__(256) void nn_exact(
    const float* __restrict__ x, const float* __restrict__ t,
    const float* __restrict__ xn, const float* __restrict__ tn,
    const float* __restrict__ bmv, float* __restrict__ out) {
  __shared__ float sv[NCB];
  __shared__ float red[256];
  __shared__ int   clist[NCB];
  __shared__ int   cnt;
  __shared__ float rv[128];
  __shared__ int   ri[128];

  const int row = blockIdx.x;
  const int tid = threadIdx.x;

  float lmin = FLT_MAX;
  for (int e = tid; e < NCB; e += 256) {
    float v = bmv[(size_t)row * NCB + e];
    sv[e] = v;
    lmin = fminf(lmin, v);
  }
  if (tid == 0) cnt = 0;
  red[tid] = lmin;
  __syncthreads();
  for (int s = 128; s >= 1; s >>= 1) {
    if (tid < s) red[tid] = fminf(red[tid], red[tid + s]);
    __syncthreads();
  }
  float g = red[0];

  for (int e = tid; e < NCB; e += 256) {
    if (sv[e] <= g + MARGIN) {
      int p = atomicAdd(&cnt, 1);
      clist[p] = e;
    }
  }
  __syncthreads();
  const int nc = cnt;

  float best = FLT_MAX;
  int   bidx = 0x7FFFFFFF;
  const float xnr = xn[row];
  const float* xrow = x + (size_t)row * DDIM;

  for (int ci = 0; ci < nc; ++ci) {
    int cbk = clist[ci];
    if (tid < 128) {
      int col = cbk * 128 + tid;
      const float* trow = t + (size_t)col * DDIM;
      float acc = 0.0f;
      // serial k-ascending fp32 FMA chain (round-1-proven accuracy)
      for (int kq = 0; kq < DDIM; kq += 4) {
        float4 xv = *(const float4*)(xrow + kq);
        float4 tv = *(const float4*)(trow + kq);
        acc = fmaf(xv.x, tv.x, acc);
        acc = fmaf(xv.y, tv.y, acc);
        acc = fmaf(xv.z, tv.z, acc);
        acc = fmaf(xv.w, tv.w, acc);
      }
      float d2 = xnr + tn[col] - 2.0f * acc;
      if (d2 < best || (d2 == best && col < bidx)) { best = d2; bidx = col; }
    }
  }
  if (tid < 128) { rv[tid] = best; ri[tid] = bidx; }
  __syncthreads();
  for (int s = 64; s >= 1; s >>= 1) {
    if (tid < s) {
      float vo = rv[tid + s]; int io = ri[tid + s];
      if (vo < rv[tid] || (vo == rv[tid] && io < ri[tid])) { rv[tid] = vo; ri[tid] = io; }
    }
    __syncthreads();
  }
  if (tid == 0) {
    out[row] = sqrtf(fmaxf(rv[0], 0.0f));
    out[N_ROWS + row] = (float)ri[0];
  }
}

// ---------------------------------------------------------------------------
// Fallback (round-1 fp32 path) in case ws is too small for the bf16 pipeline
// ---------------------------------------------------------------------------
#define BM 64
#define BN 64
#define KC 16
#define S_STRIPS 32
#define PADM 68

__global__ __launch_bounds__(256) void nn_main_fb(
    const float* __restrict__ x, const float* __restrict__ t,
    const float* __restrict__ xn, const float* __restrict__ tn,
    float* __restrict__ pmin, int* __restrict__ pidx) {
  __shared__ float sx[KC][PADM];
  __shared__ float st[KC][PADM];
  const int tid = threadIdx.x;
  const int rb = blockIdx.x;
  const int strip = blockIdx.y;
  const int tx = tid & 15, ty = tid >> 4;
  const int row0 = rb * BM;
  const int col_start = strip * (M_TGT / S_STRIPS);
  const int ntiles = (M_TGT / S_STRIPS) / BN;
  const int srow = tid >> 2;
  const int kq = (tid & 3) * 4;

  float runMin[4]; int runIdx[4];
  #pragma unroll
  for (int r = 0; r < 4; ++r) { runMin[r] = FLT_MAX; runIdx[r] = 0; }
  float xnr[4];
  #pragma unroll
  for (int r = 0; r < 4; ++r) xnr[r] = xn[row0 + ty * 4 + r];

  for (int tile = 0; tile < ntiles; ++tile) {
    const int cbk = col_start + tile * BN;
    float acc[4][4];
    #pragma unroll
    for (int r = 0; r < 4; ++r)
      #pragma unroll
      for (int c = 0; c < 4; ++c) acc[r][c] = 0.0f;
    #pragma unroll 1
    for (int kc = 0; kc < DDIM; kc += KC) {
      float4 xv = *(const float4*)(x + (size_t)(row0 + srow) * DDIM + kc + kq);
      float4 tv = *(const float4*)(t + (size_t)(cbk + srow) * DDIM + kc + kq);
      __syncthreads();
      sx[kq + 0][srow] = xv.x; sx[kq + 1][srow] = xv.y;
      sx[kq + 2][srow] = xv.z; sx[kq + 3][srow] = xv.w;
      st[kq + 0][srow] = tv.x; st[kq + 1][srow] = tv.y;
      st[kq + 2][srow] = tv.z; st[kq + 3][srow] = tv.w;
      __syncthreads();
      #pragma unroll
      for (int k = 0; k < KC; ++k) {
        float4 xa = *(const float4*)&sx[k][ty * 4];
        float4 tb = *(const float4*)&st[k][tx * 4];
        float xr[4] = {xa.x, xa.y, xa.z, xa.w};
        float tc[4] = {tb.x, tb.y, tb.z, tb.w};
        #pragma unroll
        for (int r = 0; r < 4; ++r)
          #pragma unroll
          for (int c = 0; c < 4; ++c)
            acc[r][c] = fmaf(xr[r], tc[c], acc[r][c]);
      }
    }
    #pragma unroll
    for (int r = 0; r < 4; ++r)
      #pragma unroll
      for (int c = 0; c < 4; ++c) {
        int col = cbk + tx * 4 + c;
        float d2 = xnr[r] + tn[col] - 2.0f * acc[r][c];
        if (d2 < runMin[r]) { runMin[r] = d2; runIdx[r] = col; }
      }
  }
  __syncthreads();
  float* redv = &sx[0][0];
  int*   redi = (int*)&st[0][0];
  #pragma unroll
  for (int r = 0; r < 4; ++r) {
    int lrow = ty * 4 + r;
    redv[lrow * 16 + tx] = runMin[r];
    redi[lrow * 16 + tx] = runIdx[r];
  }
  __syncthreads();
  if (tid < 64) {
    float best = FLT_MAX; int bi = 0;
    #pragma unroll
    for (int j = 0; j < 16; ++j) {
      float v = redv[tid * 16 + j];
      int   i = redi[tid * 16 + j];
      if (v < best || (v == best && i < bi)) { best = v; bi = i; }
    }
    int grow = row0 + tid;
    pmin[(size_t)grow * S_STRIPS + strip] = best;
    pidx[(size_t)grow * S_STRIPS + strip] = bi;
  }
}

__global__ __launch_bounds__(256) void reduce_final_fb(
    const float* __restrict__ pmin, const int* __restrict__ pidx,
    float* __restrict__ out) {
  int row = blockIdx.x * 256 + threadIdx.x;
  if (row >= N_ROWS) return;
  float best = FLT_MAX; int bi = 0;
  #pragma unroll 4
  for (int s = 0; s < S_STRIPS; ++s) {
    float v = pmin[(size_t)row * S_STRIPS + s];
    int   i = pidx[(size_t)row * S_STRIPS + s];
    if (v < best || (v == best && i < bi)) { best = v; bi = i; }
  }
  out[row] = sqrtf(fmaxf(best, 0.0f));
  out[N_ROWS + row] = (float)bi;
}

// ---------------------------------------------------------------------------
extern "C" void kernel_launch(void* const* d_in, const int* in_sizes, int n_in,
                              void* d_out, int out_size, void* d_ws, size_t ws_size,
                              hipStream_t stream) {
  const float* x = (const float*)d_in[0];
  const float* t = (const float*)d_in[1];
  float* ws = (float*)d_ws;
  float* out = (float*)d_out;

  float* xn = ws;                       // 4096
  float* tn = ws + N_ROWS;              // 65536

  // fast-path ws layout (floats): xn | tn | bmv[4096*512] | xb | tb
  const size_t f_bmv = (size_t)N_ROWS + M_TGT;
  const size_t f_xb  = f_bmv + (size_t)N_ROWS * NCB;
  const size_t f_tb  = f_xb + ((size_t)N_ROWS * DDIM) / 2;       // bf16 halves
  const size_t need_bytes = (f_tb + ((size_t)M_TGT * DDIM) / 2) * sizeof(float);

  norms_kernel<<<(N_ROWS + M_TGT) / 4, 256, 0, stream>>>(x, t, xn, tn);

  if (ws_size >= need_bytes) {
    float* bmv = ws + f_bmv;
    unsigned short* xb = (unsigned short*)(ws + f_xb);
    unsigned short* tb = (unsigned short*)(ws + f_tb);

    int n8x = (N_ROWS * DDIM) / 8;      // 131072
    int n8t = (M_TGT * DDIM) / 8;       // 2097152
    convert_bf16_kernel<<<(n8x + 255) / 256, 256, 0, stream>>>(x, xb, n8x);
    convert_bf16_kernel<<<(n8t + 255) / 256, 256, 0, stream>>>(t, tb, n8t);

    nn_gemm_bf16<<<(N_ROWS / GBM) * NCB, 256, 0, stream>>>(xb, tb, tn, bmv);

    nn_exact<<<N_ROWS, 256, 0, stream>>>(x, t, xn, tn, bmv, out);
  } else {
    float* pmin = ws + N_ROWS + M_TGT;
    int*   pidx = (int*)(ws + N_ROWS + M_TGT + (size_t)N_ROWS * S_STRIPS);
    dim3 grid(N_ROWS / BM, S_STRIPS);
    nn_main_fb<<<grid, 256, 0, stream>>>(x, t, xn, tn, pmin, pidx);
    reduce_final_fb<<<(N_ROWS + 255) / 256, 256, 0, stream>>>(pmin, pidx, out);
  }
}

// Round 3
// 297.691 us; speedup vs baseline: 6.7281x; 1.1050x over previous
//
#include <hip/hip_runtime.h>
#include <float.h>
#include <math.h>

#define N_ROWS 4096
#define M_TGT  65536
#define DDIM   256

// ---------------------------------------------------------------------------
// Shared types/helpers
// ---------------------------------------------------------------------------
typedef short bf16x8 __attribute__((ext_vector_type(8)));
typedef float f32x4 __attribute__((ext_vector_type(4)));
typedef unsigned short ushort4_t __attribute__((ext_vector_type(4)));
typedef unsigned short ushort8_t __attribute__((ext_vector_type(8)));

__device__ inline unsigned short f2bf(float f) {
  union { float f; unsigned u; } c; c.f = f;
  unsigned u = c.u;
  unsigned r = (u + 0x7FFFu + ((u >> 16) & 1u)) >> 16;  // RNE
  return (unsigned short)r;
}

__device__ inline void gload_lds16(const void* g, void* l) {
  __builtin_amdgcn_global_load_lds(
      (const __attribute__((address_space(1))) void*)g,
      (__attribute__((address_space(3))) void*)l, 16, 0, 0);
}

// ---------------------------------------------------------------------------
// Kernel: fused fp32->bf16 convert + row norm. One wave per row (D=256 =
// 64 lanes x float4). Saves a separate 68MB norm pass.
// ---------------------------------------------------------------------------
__global__ __launch_bounds__(256) void conv_norm_kernel(
    const float* __restrict__ src, unsigned short* __restrict__ dst,
    float* __restrict__ nrm, int nrows) {
  int wave = threadIdx.x >> 6;
  int lane = threadIdx.x & 63;
  int row  = blockIdx.x * 4 + wave;
  if (row >= nrows) return;
  const float* s = src + (size_t)row * DDIM;
  float4 v = *(const float4*)(s + lane * 4);
  float ss = v.x * v.x + v.y * v.y + v.z * v.z + v.w * v.w;
  ushort4_t o;
  o[0] = f2bf(v.x); o[1] = f2bf(v.y); o[2] = f2bf(v.z); o[3] = f2bf(v.w);
  *(ushort4_t*)(dst + (size_t)row * DDIM + lane * 4) = o;
  #pragma unroll
  for (int off = 32; off > 0; off >>= 1) ss += __shfl_xor(ss, off, 64);
  if (lane == 0) nrm[row] = ss;
}

// ---------------------------------------------------------------------------
// Kernel: bf16 MFMA screening GEMM. 128x128 tile, 4 waves (2x2), BK=64.
// Conflict-free LDS: row len 128B = 8 x 16B slots; logical k-chunk s stored
// at phys slot p = s ^ (row&7). Bank-start = 4p; 16 consecutive rows cover
// all 8 slot values exactly twice -> 2-way (free).
// Stage side: global_load_lds writes linearly (chunk q -> row=q>>3, p=q&7),
// so the SOURCE address is pre-permuted with the same involution (rule 21).
// Block order: per-XCD chunks sweep row-blocks fastest so each 64KB B col-
// tile stays L2-hot across the 32 row-blocks; xb (2MB) is L2-resident.
// Output: per (row, 128-col-tile) min of (tn[col] - 2*dot_bf16).
// ---------------------------------------------------------------------------
#define GBM 128
#define GBN 128
#define GBK 64
#define NCB (M_TGT / GBN)          // 512 col tiles
#define MARGIN 1.5f

__global__ __launch_bounds__(256) void nn_gemm_bf16(
    const unsigned short* __restrict__ xb, const unsigned short* __restrict__ tb,
    const float* __restrict__ tn, float* __restrict__ bmv) {
  __shared__ unsigned short sA[GBM * GBK];   // 16 KB
  __shared__ unsigned short sB[GBN * GBK];   // 16 KB

  const int tid  = threadIdx.x;
  const int lane = tid & 63;
  const int wid  = tid >> 6;
  const int wr   = wid >> 1, wc = wid & 1;

  // XCD-aware, B-panel-reuse ordering (bijective: 16384 = 8 XCD * 64 cb * 32 rb)
  const int bid = blockIdx.x;
  const int xcd = bid & 7;
  const int wgi = bid >> 3;
  const int rb  = wgi & 31;                  // fastest within XCD
  const int cb  = xcd * 64 + (wgi >> 5);
  const int row0 = rb * GBM;
  const int col0 = cb * GBN;

  // staging map: chunk q = i*256 + tid; row=q>>3, phys slot=q&7,
  // logical slot s = (q&7) ^ (row&7)
  int rq[4], sq[4];
  #pragma unroll
  for (int i = 0; i < 4; ++i) {
    int q = i * 256 + tid;
    rq[i] = q >> 3;
    sq[i] = (q & 7) ^ (rq[i] & 7);
  }
  char* sAc = (char*)sA;
  char* sBc = (char*)sB;

  f32x4 acc[4][4];
  const f32x4 zero = {0.0f, 0.0f, 0.0f, 0.0f};
  #pragma unroll
  for (int m = 0; m < 4; ++m)
    #pragma unroll
    for (int n = 0; n < 4; ++n) acc[m][n] = zero;

  const int cg = lane >> 4;

  #pragma unroll
  for (int kc = 0; kc < DDIM; kc += GBK) {
    __syncthreads();   // previous step's LDS reads complete
    #pragma unroll
    for (int i = 0; i < 4; ++i)
      gload_lds16(xb + (size_t)(row0 + rq[i]) * DDIM + kc + sq[i] * 8,
                  sAc + i * 4096 + wid * 1024);
    #pragma unroll
    for (int i = 0; i < 4; ++i)
      gload_lds16(tb + (size_t)(col0 + rq[i]) * DDIM + kc + sq[i] * 8,
                  sBc + i * 4096 + wid * 1024);
    __syncthreads();   // vmcnt(0) drained before barrier -> data ready

    bf16x8 af[4][2], bfr[4][2];
    #pragma unroll
    for (int m = 0; m < 4; ++m) {
      int r = wr * 64 + m * 16 + (lane & 15);
      #pragma unroll
      for (int kk = 0; kk < 2; ++kk) {
        int s8 = kk * 4 + cg;
        int p  = s8 ^ (r & 7);
        af[m][kk] = *(const bf16x8*)(sAc + r * 128 + p * 16);
      }
    }
    #pragma unroll
    for (int n = 0; n < 4; ++n) {
      int r = wc * 64 + n * 16 + (lane & 15);
      #pragma unroll
      for (int kk = 0; kk < 2; ++kk) {
        int s8 = kk * 4 + cg;
        int p  = s8 ^ (r & 7);
        bfr[n][kk] = *(const bf16x8*)(sBc + r * 128 + p * 16);
      }
    }
    #pragma unroll
    for (int kk = 0; kk < 2; ++kk)
      #pragma unroll
      for (int m = 0; m < 4; ++m)
        #pragma unroll
        for (int n = 0; n < 4; ++n)
          acc[m][n] = __builtin_amdgcn_mfma_f32_16x16x32_bf16(
              af[m][kk], bfr[n][kk], acc[m][n], 0, 0, 0);
  }

  // ---- epilogue: per-row min of (tn[col] - 2*dot) over this 128-col tile ----
  float tnc[4];
  #pragma unroll
  for (int n = 0; n < 4; ++n)
    tnc[n] = tn[col0 + wc * 64 + n * 16 + (lane & 15)];

  __syncthreads();                  // done reading sA/sB as tiles
  float* emin = (float*)sA;         // [2 wc][128 rows]

  #pragma unroll
  for (int m = 0; m < 4; ++m) {
    float bv[4];
    #pragma unroll
    for (int j = 0; j < 4; ++j) bv[j] = FLT_MAX;
    #pragma unroll
    for (int n = 0; n < 4; ++n)
      #pragma unroll
      for (int j = 0; j < 4; ++j)
        bv[j] = fminf(bv[j], tnc[n] - 2.0f * acc[m][n][j]);
    #pragma unroll
    for (int off = 1; off < 16; off <<= 1)
      #pragma unroll
      for (int j = 0; j < 4; ++j)
        bv[j] = fminf(bv[j], __shfl_xor(bv[j], off, 64));
    if ((lane & 15) == 0) {
      int rbase = wr * 64 + m * 16 + (lane >> 4) * 4;
      #pragma unroll
      for (int j = 0; j < 4; ++j)
        emin[wc * 128 + rbase + j] = bv[j];
    }
  }
  __syncthreads();
  if (tid < 128) {
    float v = fminf(emin[tid], emin[128 + tid]);
    bmv[(size_t)(row0 + tid) * NCB + cb] = v;
  }
}

// ---------------------------------------------------------------------------
// Kernel: per-row candidate selection + exact fp32 verification.
// One block per row; verify 2 candidate tiles concurrently (128 thr each).
// ---------------------------------------------------------------------------
__global__ __launch_bounds__(256) void nn_exact(
    const float* __restrict__ x, const float* __restrict__ t,
    const float* __restrict__ xn, const float* __restrict__ tn,
    const float* __restrict__ bmv, float* __restrict__ out) {
  __shared__ float sv[NCB];
  __shared__ int   clist[NCB];
  __shared__ int   cnt;
  __shared__ float wmin[4];
  __shared__ float rv[256];
  __shared__ int   ri[256];

  const int row = blockIdx.x;
  const int tid = threadIdx.x;

  if (tid == 0) cnt = 0;
  float lmin = FLT_MAX;
  #pragma unroll
  for (int e = tid; e < NCB; e += 256) {
    float v = bmv[(size_t)row * NCB + e];
    sv[e] = v;
    lmin = fminf(lmin, v);
  }
  #pragma unroll
  for (int off = 32; off > 0; off >>= 1) lmin = fminf(lmin, __shfl_xor(lmin, off, 64));
  if ((tid & 63) == 0) wmin[tid >> 6] = lmin;
  __syncthreads();
  const float g = fminf(fminf(wmin[0], wmin[1]), fminf(wmin[2], wmin[3]));

  #pragma unroll
  for (int e = tid; e < NCB; e += 256) {
    if (sv[e] <= g + MARGIN) {
      int p = atomicAdd(&cnt, 1);
      clist[p] = e;
    }
  }
  __syncthreads();
  const int nc = cnt;

  float best = FLT_MAX;
  int   bidx = 0x7FFFFFFF;
  const float xnr = xn[row];
  const float* xrow = x + (size_t)row * DDIM;

  for (int ci = 0; ci < nc; ci += 2) {
    int slot = ci + (tid >> 7);
    if (slot < nc) {
      int col = clist[slot] * 128 + (tid & 127);
      const float* trow = t + (size_t)col * DDIM;
      float acc = 0.0f;
      // serial k-ascending fp32 FMA chain (deterministic, exact per col)
      for (int kq = 0; kq < DDIM; kq += 4) {
        float4 xv = *(const float4*)(xrow + kq);
        float4 tv = *(const float4*)(trow + kq);
        acc = fmaf(xv.x, tv.x, acc);
        acc = fmaf(xv.y, tv.y, acc);
        acc = fmaf(xv.z, tv.z, acc);
        acc = fmaf(xv.w, tv.w, acc);
      }
      float d2 = xnr + tn[col] - 2.0f * acc;
      if (d2 < best || (d2 == best && col < bidx)) { best = d2; bidx = col; }
    }
  }
  rv[tid] = best; ri[tid] = bidx;
  __syncthreads();
  for (int s = 128; s >= 1; s >>= 1) {
    if (tid < s) {
      float vo = rv[tid + s]; int io = ri[tid + s];
      if (vo < rv[tid] || (vo == rv[tid] && io < ri[tid])) { rv[tid] = vo; ri[tid] = io; }
    }
    __syncthreads();
  }
  if (tid == 0) {
    out[row] = sqrtf(fmaxf(rv[0], 0.0f));
    out[N_ROWS + row] = (float)ri[0];
  }
}

// ---------------------------------------------------------------------------
// Fallback fp32 path (if ws too small) — round-1 proven
// ---------------------------------------------------------------------------
#define BM 64
#define BN 64
#define KC 16
#define S_STRIPS 32
#define PADM 68

__global__ __launch_bounds__(256) void norms_kernel_fb(
    const float* __restrict__ x, const float* __restrict__ t,
    float* __restrict__ xn, float* __restrict__ tn) {
  int wave = threadIdx.x >> 6;
  int lane = threadIdx.x & 63;
  int row  = blockIdx.x * 4 + wave;
  const float* src; float* dst;
  if (row < N_ROWS) { src = x + (size_t)row * DDIM; dst = xn + row; }
  else {
    int r = row - N_ROWS;
    if (r >= M_TGT) return;
    src = t + (size_t)r * DDIM; dst = tn + r;
  }
  float4 v = *(const float4*)(src + lane * 4);
  float s = v.x * v.x + v.y * v.y + v.z * v.z + v.w * v.w;
  #pragma unroll
  for (int off = 32; off > 0; off >>= 1) s += __shfl_xor(s, off, 64);
  if (lane == 0) *dst = s;
}

__global__ __launch_bounds__(256) void nn_main_fb(
    const float* __restrict__ x, const float* __restrict__ t,
    const float* __restrict__ xn, const float* __restrict__ tn,
    float* __restrict__ pmin, int* __restrict__ pidx) {
  __shared__ float sx[KC][PADM];
  __shared__ float st[KC][PADM];
  const int tid = threadIdx.x;
  const int rb = blockIdx.x;
  const int strip = blockIdx.y;
  const int tx = tid & 15, ty = tid >> 4;
  const int row0 = rb * BM;
  const int col_start = strip * (M_TGT / S_STRIPS);
  const int ntiles = (M_TGT / S_STRIPS) / BN;
  const int srow = tid >> 2;
  const int kq = (tid & 3) * 4;

  float runMin[4]; int runIdx[4];
  #pragma unroll
  for (int r = 0; r < 4; ++r) { runMin[r] = FLT_MAX; runIdx[r] = 0; }
  float xnr[4];
  #pragma unroll
  for (int r = 0; r < 4; ++r) xnr[r] = xn[row0 + ty * 4 + r];

  for (int tile = 0; tile < ntiles; ++tile) {
    const int cbk = col_start + tile * BN;
    float acc[4][4];
    #pragma unroll
    for (int r = 0; r < 4; ++r)
      #pragma unroll
      for (int c = 0; c < 4; ++c) acc[r][c] = 0.0f;
    #pragma unroll 1
    for (int kc = 0; kc < DDIM; kc += KC) {
      float4 xv = *(const float4*)(x + (size_t)(row0 + srow) * DDIM + kc + kq);
      float4 tv = *(const float4*)(t + (size_t)(cbk + srow) * DDIM + kc + kq);
      __syncthreads();
      sx[kq + 0][srow] = xv.x; sx[kq + 1][srow] = xv.y;
      sx[kq + 2][srow] = xv.z; sx[kq + 3][srow] = xv.w;
      st[kq + 0][srow] = tv.x; st[kq + 1][srow] = tv.y;
      st[kq + 2][srow] = tv.z; st[kq + 3][srow] = tv.w;
      __syncthreads();
      #pragma unroll
      for (int k = 0; k < KC; ++k) {
        float4 xa = *(const float4*)&sx[k][ty * 4];
        float4 tb2 = *(const float4*)&st[k][tx * 4];
        float xr[4] = {xa.x, xa.y, xa.z, xa.w};
        float tc[4] = {tb2.x, tb2.y, tb2.z, tb2.w};
        #pragma unroll
        for (int r = 0; r < 4; ++r)
          #pragma unroll
          for (int c = 0; c < 4; ++c)
            acc[r][c] = fmaf(xr[r], tc[c], acc[r][c]);
      }
    }
    #pragma unroll
    for (int r = 0; r < 4; ++r)
      #pragma unroll
      for (int c = 0; c < 4; ++c) {
        int col = cbk + tx * 4 + c;
        float d2 = xnr[r] + tn[col] - 2.0f * acc[r][c];
        if (d2 < runMin[r]) { runMin[r] = d2; runIdx[r] = col; }
      }
  }
  __syncthreads();
  float* redv = &sx[0][0];
  int*   redi = (int*)&st[0][0];
  #pragma unroll
  for (int r = 0; r < 4; ++r) {
    int lrow = ty * 4 + r;
    redv[lrow * 16 + tx] = runMin[r];
    redi[lrow * 16 + tx] = runIdx[r];
  }
  __syncthreads();
  if (tid < 64) {
    float best = FLT_MAX; int bi = 0;
    #pragma unroll
    for (int j = 0; j < 16; ++j) {
      float v = redv[tid * 16 + j];
      int   i = redi[tid * 16 + j];
      if (v < best || (v == best && i < bi)) { best = v; bi = i; }
    }
    int grow = row0 + tid;
    pmin[(size_t)grow * S_STRIPS + strip] = best;
    pidx[(size_t)grow * S_STRIPS + strip] = bi;
  }
}

__global__ __launch_bounds__(256) void reduce_final_fb(
    const float* __restrict__ pmin, const int* __restrict__ pidx,
    float* __restrict__ out) {
  int row = blockIdx.x * 256 + threadIdx.x;
  if (row >= N_ROWS) return;
  float best = FLT_MAX; int bi = 0;
  #pragma unroll 4
  for (int s = 0; s < S_STRIPS; ++s) {
    float v = pmin[(size_t)row * S_STRIPS + s];
    int   i = pidx[(size_t)row * S_STRIPS + s];
    if (v < best || (v == best && i < bi)) { best = v; bi = i; }
  }
  out[row] = sqrtf(fmaxf(best, 0.0f));
  out[N_ROWS + row] = (float)bi;
}

// ---------------------------------------------------------------------------
extern "C" void kernel_launch(void* const* d_in, const int* in_sizes, int n_in,
                              void* d_out, int out_size, void* d_ws, size_t ws_size,
                              hipStream_t stream) {
  const float* x = (const float*)d_in[0];
  const float* t = (const float*)d_in[1];
  float* ws = (float*)d_ws;
  float* out = (float*)d_out;

  float* xn = ws;                       // 4096
  float* tn = ws + N_ROWS;              // 65536

  // fast-path ws layout (floats): xn | tn | bmv[4096*512] | xb | tb
  const size_t f_bmv = (size_t)N_ROWS + M_TGT;
  const size_t f_xb  = f_bmv + (size_t)N_ROWS * NCB;
  const size_t f_tb  = f_xb + ((size_t)N_ROWS * DDIM) / 2;       // bf16 halves
  const size_t need_bytes = (f_tb + ((size_t)M_TGT * DDIM) / 2) * sizeof(float);

  if (ws_size >= need_bytes) {
    float* bmv = ws + f_bmv;
    unsigned short* xb = (unsigned short*)(ws + f_xb);
    unsigned short* tb = (unsigned short*)(ws + f_tb);

    conv_norm_kernel<<<(N_ROWS + 3) / 4, 256, 0, stream>>>(x, xb, xn, N_ROWS);
    conv_norm_kernel<<<(M_TGT + 3) / 4, 256, 0, stream>>>(t, tb, tn, M_TGT);

    nn_gemm_bf16<<<(N_ROWS / GBM) * NCB, 256, 0, stream>>>(xb, tb, tn, bmv);

    nn_exact<<<N_ROWS, 256, 0, stream>>>(x, t, xn, tn, bmv, out);
  } else {
    norms_kernel_fb<<<(N_ROWS + M_TGT) / 4, 256, 0, stream>>>(x, t, xn, tn);
    float* pmin = ws + N_ROWS + M_TGT;
    int*   pidx = (int*)(ws + N_ROWS + M_TGT + (size_t)N_ROWS * S_STRIPS);
    dim3 grid(N_ROWS / BM, S_STRIPS);
    nn_main_fb<<<grid, 256, 0, stream>>>(x, t, xn, tn, pmin, pidx);
    reduce_final_fb<<<(N_ROWS + 255) / 256, 256, 0, stream>>>(pmin, pidx, out);
  }
}